// Round 11
// baseline (178.467 us; speedup 1.0000x reference)
//
#include <hip/hip_runtime.h>
#include <hip/hip_bf16.h>
#include <math.h>

#define TPB 256

typedef __attribute__((ext_vector_type(8))) short s16x8;
typedef __attribute__((ext_vector_type(4))) float f32x4;

#define MFMA16(a, b, c) __builtin_amdgcn_mfma_f32_16x16x32_bf16((a), (b), (c), 0, 0, 0)

// ---------------- workspace layout (float offsets) ----------------
constexpr unsigned OFF_P    = 0u;                     // p    [4096][256] (relu'd)
constexpr unsigned OFF_K    = OFF_P    + 4096u*256u;  // k    [4096][64]
constexpr unsigned OFF_PA   = OFF_K    + 4096u*64u;   // pa   [4096][64]
constexpr unsigned OFF_R    = OFF_PA   + 4096u*64u;   // r    [512][64]
constexpr unsigned OFF_RA   = OFF_R    + 512u*64u;    // ra   [512][64]
constexpr unsigned OFF_SR   = OFF_RA   + 512u*64u;    // SR   [512][64]  (exact, k3h)
constexpr unsigned OFF_PMAX = OFF_SR   + 512u*64u;    // PMAX [64] (atomicMax, zeroed by k1 tail)
constexpr unsigned OFF_SP   = OFF_PMAX + 64u;         // SP   [4096][64] (exact, k3h)

// scalar RNE fp32 -> bf16
__device__ __forceinline__ short f2bf(float x) {
  union { float f; unsigned u; } v; v.f = x;
  unsigned r = v.u + 0x7FFFu + ((v.u >> 16) & 1u);
  return (short)(r >> 16);
}
// packed RNE: 2 floats -> 2 bf16 in one dword
__device__ __forceinline__ unsigned pkbf(float a, float b) {
  __hip_bfloat162 h = __float22bfloat162_rn(make_float2(a, b));
  union { __hip_bfloat162 h2; unsigned u; } v; v.h2 = h;
  return v.u;
}
union U8 { s16x8 s; unsigned u[4]; };

// ============================================================================
// K1: p = relu(protein @ Wc^T + bc)  via bf16 MFMA 16x16x32.
// 512 GEMM blocks (tile 32x64) -> 2 blocks/CU. BK=64, 16 chunks, prefetch.
// Tail block 512: zero PMAX.
// ============================================================================
__global__ __launch_bounds__(TPB, 2) void k1_gemm(
    const float* __restrict__ prot, const float* __restrict__ Wc,
    const float* __restrict__ bc,   float* __restrict__ ws)
{
  int bid = blockIdx.x;
  int tid = threadIdx.x;
  if (bid >= 512) {
    if (tid < 16)
      *(float4*)&ws[OFF_PMAX + tid * 4] = make_float4(0.f, 0.f, 0.f, 0.f);
    return;
  }

  __shared__ __align__(16) short Asm[32 * 72];    // [m][64+8] bf16
  __shared__ __align__(16) short Bsm[64 * 72];    // [n][64+8] bf16

  int m0 = (bid >> 2) * 32;
  int n0 = (bid & 3) * 64;
  int wave = tid >> 6, lane = tid & 63;
  int wm = (wave & 1) * 16, wn = (wave >> 1) * 32;   // wave tile 16x32
  int lm = lane & 15, quad = lane >> 4;

  int arow = tid >> 3, aseg = (tid & 7) * 8;    // A: 32 rows x 8 x 8 floats
  int brow = tid >> 2, bseg = (tid & 3) * 16;   // B: 64 rows x 4 x 16 floats

  const float* Ag = prot + (size_t)(m0 + arow) * 1024 + aseg;
  const float* Bg = Wc   + (size_t)(n0 + brow) * 1024 + bseg;

  float4 a4[2], b4[4];
#pragma unroll
  for (int i = 0; i < 2; ++i) a4[i] = *(const float4*)(Ag + i * 4);
#pragma unroll
  for (int i = 0; i < 4; ++i) b4[i] = *(const float4*)(Bg + i * 4);

  f32x4 acc[2] = {};

  for (int kc = 0; kc < 16; ++kc) {
    __syncthreads();                    // previous chunk's frag reads done
    {
      U8 s;
      s.u[0] = pkbf(a4[0].x, a4[0].y); s.u[1] = pkbf(a4[0].z, a4[0].w);
      s.u[2] = pkbf(a4[1].x, a4[1].y); s.u[3] = pkbf(a4[1].z, a4[1].w);
      *(s16x8*)&Asm[arow * 72 + aseg] = s.s;
    }
#pragma unroll
    for (int h = 0; h < 2; ++h) {
      U8 s;
      s.u[0] = pkbf(b4[h*2].x,   b4[h*2].y);
      s.u[1] = pkbf(b4[h*2].z,   b4[h*2].w);
      s.u[2] = pkbf(b4[h*2+1].x, b4[h*2+1].y);
      s.u[3] = pkbf(b4[h*2+1].z, b4[h*2+1].w);
      *(s16x8*)&Bsm[brow * 72 + bseg + h * 8] = s.s;
    }
    if (kc < 15) {                      // prefetch next chunk over this MFMA
#pragma unroll
      for (int i = 0; i < 2; ++i) a4[i] = *(const float4*)(Ag + (kc + 1) * 64 + i * 4);
#pragma unroll
      for (int i = 0; i < 4; ++i) b4[i] = *(const float4*)(Bg + (kc + 1) * 64 + i * 4);
    }
    __syncthreads();
#pragma unroll
    for (int ks = 0; ks < 2; ++ks) {
      s16x8 af = *(const s16x8*)&Asm[(wm + lm) * 72 + ks * 32 + quad * 8];
#pragma unroll
      for (int ni = 0; ni < 2; ++ni) {
        s16x8 bfv = *(const s16x8*)&Bsm[(wn + ni * 16 + lm) * 72 + ks * 32 + quad * 8];
        acc[ni] = MFMA16(af, bfv, acc[ni]);
      }
    }
  }

  // epilogue: C/D layout col=lane&15, row=quad*4+reg
#pragma unroll
  for (int ni = 0; ni < 2; ++ni) {
    int col = n0 + wn + ni * 16 + lm;
    float bcv = bc[col];
#pragma unroll
    for (int r = 0; r < 4; ++r) {
      int row = m0 + wm + quad * 4 + r;
      ws[OFF_P + (unsigned)row * 256u + col] = fmaxf(acc[ni][r] + bcv, 0.f);
    }
  }
}

// ============================================================================
// K2: two heads via bf16 MFMA, 144 blocks x 32 rows, both stages fused.
// ============================================================================
__global__ __launch_bounds__(TPB, 2) void k2_heads(
    const float* __restrict__ reactions,
    const float* __restrict__ W1,  const float* __restrict__ b1,
    const float* __restrict__ W2,  const float* __restrict__ b2,
    const float* __restrict__ Wpa, const float* __restrict__ bpa,
    const float* __restrict__ Wra, const float* __restrict__ bra,
    float* __restrict__ ws)
{
  __shared__ __align__(16) short Asm[32 * 264];   // src rows [32][256+8]
  __shared__ __align__(16) short Bsm[64 * 264];   // W1/W2 [64][256+8]
  __shared__ __align__(16) short Ksm[32 * 72];    // k-tile bf16 [32][64+8]
  __shared__ __align__(16) short Wsm[64 * 72];    // Wpa/Wra [64][64+8]
  int bid = blockIdx.x, tid = threadIdx.x;
  bool isProt = bid < 128;
  int row0 = (isProt ? bid : (bid - 128)) * 32;
  const float* src  = isProt ? (ws + OFF_P) : reactions;
  const float* Wst1 = isProt ? W1 : W2;
  const float* bv   = isProt ? b1 : b2;
  const float* Wst2 = isProt ? Wpa : Wra;
  const float* b2nd = isProt ? bpa : bra;
  float* out1 = ws + (isProt ? OFF_K : OFF_R);
  float* out2 = ws + (isProt ? OFF_PA : OFF_RA);

  {                                     // stage A [32][256] fp32 -> bf16
    int row = tid >> 3, seg = (tid & 7) * 32;
    const float* sp = src + (size_t)(row0 + row) * 256 + seg;
    float4 f[8];
#pragma unroll
    for (int i = 0; i < 8; ++i) f[i] = *(const float4*)(sp + i * 4);
#pragma unroll
    for (int i = 0; i < 4; ++i) {
      U8 s;
      s.u[0] = pkbf(f[2*i].x,   f[2*i].y);
      s.u[1] = pkbf(f[2*i].z,   f[2*i].w);
      s.u[2] = pkbf(f[2*i+1].x, f[2*i+1].y);
      s.u[3] = pkbf(f[2*i+1].z, f[2*i+1].w);
      *(s16x8*)&Asm[row * 264 + seg + i * 8] = s.s;
    }
  }
  {                                     // stage B = W1/W2 [64][256] native
    int row = tid >> 2, seg = (tid & 3) * 64;
    const float* sp = Wst1 + (size_t)row * 256 + seg;
#pragma unroll
    for (int i = 0; i < 8; ++i) {
      float4 fa = *(const float4*)(sp + i * 8);
      float4 fb = *(const float4*)(sp + i * 8 + 4);
      U8 s;
      s.u[0] = pkbf(fa.x, fa.y); s.u[1] = pkbf(fa.z, fa.w);
      s.u[2] = pkbf(fb.x, fb.y); s.u[3] = pkbf(fb.z, fb.w);
      *(s16x8*)&Bsm[row * 264 + seg + i * 8] = s.s;
    }
  }
  {                                     // stage Wpa/Wra [64][64] native
    int row = tid >> 2, seg = (tid & 3) * 16;
    const float* sp = Wst2 + (size_t)row * 64 + seg;
#pragma unroll
    for (int i = 0; i < 2; ++i) {
      float4 fa = *(const float4*)(sp + i * 8);
      float4 fb = *(const float4*)(sp + i * 8 + 4);
      U8 s;
      s.u[0] = pkbf(fa.x, fa.y); s.u[1] = pkbf(fa.z, fa.w);
      s.u[2] = pkbf(fb.x, fb.y); s.u[3] = pkbf(fb.z, fb.w);
      *(s16x8*)&Wsm[row * 72 + seg + i * 8] = s.s;
    }
  }
  __syncthreads();

  int wave = tid >> 6, lane = tid & 63;
  int lm = lane & 15, quad = lane >> 4;
  int wm = (wave >> 1) * 16, wn = (wave & 1) * 32;   // wave tile 16x32

  f32x4 acc[2] = {};
#pragma unroll
  for (int kc = 0; kc < 8; ++kc) {
    s16x8 a = *(const s16x8*)&Asm[(wm + lm) * 264 + kc * 32 + quad * 8];
#pragma unroll
    for (int ni = 0; ni < 2; ++ni) {
      s16x8 b = *(const s16x8*)&Bsm[(wn + ni * 16 + lm) * 264 + kc * 32 + quad * 8];
      acc[ni] = MFMA16(a, b, acc[ni]);
    }
  }
  // epilogue 1: k = relu(acc + b); fp32 -> ws, bf16 -> Ksm (A-layout)
#pragma unroll
  for (int ni = 0; ni < 2; ++ni) {
    int col = wn + ni * 16 + lm;
    float bb = bv[col];
#pragma unroll
    for (int r = 0; r < 4; ++r) {
      int row = wm + quad * 4 + r;
      float kv = fmaxf(acc[ni][r] + bb, 0.f);
      out1[(size_t)(row0 + row) * 64 + col] = kv;
      Ksm[row * 72 + col] = f2bf(kv);
    }
  }
  __syncthreads();

  f32x4 acc2[2] = {};
#pragma unroll
  for (int kc = 0; kc < 2; ++kc) {
    s16x8 a = *(const s16x8*)&Ksm[(wm + lm) * 72 + kc * 32 + quad * 8];
#pragma unroll
    for (int ni = 0; ni < 2; ++ni) {
      s16x8 b = *(const s16x8*)&Wsm[(wn + ni * 16 + lm) * 72 + kc * 32 + quad * 8];
      acc2[ni] = MFMA16(a, b, acc2[ni]);
    }
  }
#pragma unroll
  for (int ni = 0; ni < 2; ++ni) {
    int col = wn + ni * 16 + lm;
    float bb = b2nd[col];
#pragma unroll
    for (int r = 0; r < 4; ++r) {
      int row = wm + quad * 4 + r;
      out2[(size_t)(row0 + row) * 64 + col] = acc2[ni][r] + bb;
    }
  }
}

// ============================================================================
// K3h: HISTOGRAM interaction sums (replaces brute-force k3; R5-R10 showed
// all brute-force variants pinned at ~44us vs 10us floor).
// Per channel c: Sr[q,c] = sum_l relu(u + x_l) = u*cnt(x>-u) + sum(x>-u).
// Build 1024-bin (count,sum) histogram of the column + suffix scan; each
// output is one bin lookup. Boundary-bin error <= pop*binwidth -> ~1e-5 on
// the /4096 mean (invisible vs 3.9e-3 bf16 noise, sigmoid-damped).
// 64 blocks (one per channel): pass A = pa-hist -> SR (512 queries);
// pass B = ra-hist -> SP (4096 queries).
// ============================================================================
__global__ __launch_bounds__(TPB) void k3h_hist(float* __restrict__ ws)
{
  __shared__ float xcol[4096];          // pa column
  __shared__ float rcol[512];           // ra column
  __shared__ float hc[1025];            // bin counts -> suffix counts
  __shared__ float hs[1025];            // bin sums   -> suffix sums
  __shared__ float rmn[4], rmx[4];
  int c = blockIdx.x, tid = threadIdx.x;
  int wave = tid >> 6, lane = tid & 63;
  const float* pa = ws + OFF_PA;
  const float* ra = ws + OFF_RA;

  for (int i = tid; i < 4096; i += TPB) xcol[i] = pa[(unsigned)i * 64u + c];
  for (int i = tid; i < 512;  i += TPB) rcol[i] = ra[(unsigned)i * 64u + c];
  for (int i = tid; i < 1025; i += TPB) { hc[i] = 0.f; hs[i] = 0.f; }
  __syncthreads();

  // ---- pass A: histogram xcol (pa), queries from rcol -> SR ----
  float mn = 1e30f, mx = -1e30f;
  for (int i = tid; i < 4096; i += TPB) {
    float x = xcol[i];
    mn = fminf(mn, x); mx = fmaxf(mx, x);
  }
#pragma unroll
  for (int off = 32; off > 0; off >>= 1) {
    mn = fminf(mn, __shfl_down(mn, off));
    mx = fmaxf(mx, __shfl_down(mx, off));
  }
  if (lane == 0) { rmn[wave] = mn; rmx[wave] = mx; }
  __syncthreads();
  mn = fminf(fminf(rmn[0], rmn[1]), fminf(rmn[2], rmn[3]));
  mx = fmaxf(fmaxf(rmx[0], rmx[1]), fmaxf(rmx[2], rmx[3]));
  float w = (mx - mn) * (1.f / 1024.f);
  float invw = (w > 1e-30f) ? 1.f / w : 0.f;
  for (int i = tid; i < 4096; i += TPB) {
    float x = xcol[i];
    int b = (int)((x - mn) * invw);
    b = b < 0 ? 0 : (b > 1023 ? 1023 : b);
    atomicAdd(&hc[b], 1.f);
    atomicAdd(&hs[b], x);
  }
  __syncthreads();
  if (wave == 0) {                      // suffix scan, 16 bins/lane + shfl
    float vc[16], vs[16], sc = 0.f, ss = 0.f;
#pragma unroll
    for (int i = 0; i < 16; ++i) {
      vc[i] = hc[lane * 16 + i]; sc += vc[i];
      vs[i] = hs[lane * 16 + i]; ss += vs[i];
    }
    float tc = sc, ts = ss;
#pragma unroll
    for (int off = 1; off < 64; off <<= 1) {
      float oc = __shfl_down(tc, off);
      float os = __shfl_down(ts, off);
      if (lane + off < 64) { tc += oc; ts += os; }
    }
    float runc = tc - sc, runs = ts - ss;
#pragma unroll
    for (int i = 15; i >= 0; --i) {
      runc += vc[i]; hc[lane * 16 + i] = runc;
      runs += vs[i]; hs[lane * 16 + i] = runs;
    }
  }
  __syncthreads();                      // hc/hs = inclusive suffix; [1024]=0
  for (int q = tid; q < 512; q += TPB) {
    float u = rcol[q];
    float thr = -u;
    int b;
    if (thr < mn) b = 0;
    else { b = (int)((thr - mn) * invw) + 1; b = b > 1024 ? 1024 : b; }
    ws[OFF_SR + (unsigned)q * 64u + c] = u * hc[b] + hs[b];
  }
  __syncthreads();                      // queries done before hist reuse

  // ---- pass B: histogram rcol (ra), queries from xcol -> SP ----
  for (int i = tid; i < 1025; i += TPB) { hc[i] = 0.f; hs[i] = 0.f; }
  float mn2 = 1e30f, mx2 = -1e30f;
  for (int i = tid; i < 512; i += TPB) {
    float x = rcol[i];
    mn2 = fminf(mn2, x); mx2 = fmaxf(mx2, x);
  }
#pragma unroll
  for (int off = 32; off > 0; off >>= 1) {
    mn2 = fminf(mn2, __shfl_down(mn2, off));
    mx2 = fmaxf(mx2, __shfl_down(mx2, off));
  }
  __syncthreads();                      // rmn/rmx reuse safe after this
  if (lane == 0) { rmn[wave] = mn2; rmx[wave] = mx2; }
  __syncthreads();
  mn2 = fminf(fminf(rmn[0], rmn[1]), fminf(rmn[2], rmn[3]));
  mx2 = fmaxf(fmaxf(rmx[0], rmx[1]), fmaxf(rmx[2], rmx[3]));
  float w2 = (mx2 - mn2) * (1.f / 1024.f);
  float invw2 = (w2 > 1e-30f) ? 1.f / w2 : 0.f;
  for (int i = tid; i < 512; i += TPB) {
    float x = rcol[i];
    int b = (int)((x - mn2) * invw2);
    b = b < 0 ? 0 : (b > 1023 ? 1023 : b);
    atomicAdd(&hc[b], 1.f);
    atomicAdd(&hs[b], x);
  }
  __syncthreads();
  if (wave == 0) {
    float vc[16], vs[16], sc = 0.f, ss = 0.f;
#pragma unroll
    for (int i = 0; i < 16; ++i) {
      vc[i] = hc[lane * 16 + i]; sc += vc[i];
      vs[i] = hs[lane * 16 + i]; ss += vs[i];
    }
    float tc = sc, ts = ss;
#pragma unroll
    for (int off = 1; off < 64; off <<= 1) {
      float oc = __shfl_down(tc, off);
      float os = __shfl_down(ts, off);
      if (lane + off < 64) { tc += oc; ts += os; }
    }
    float runc = tc - sc, runs = ts - ss;
#pragma unroll
    for (int i = 15; i >= 0; --i) {
      runc += vc[i]; hc[lane * 16 + i] = runc;
      runs += vs[i]; hs[lane * 16 + i] = runs;
    }
  }
  __syncthreads();
  for (int l = tid; l < 4096; l += TPB) {
    float v = xcol[l];
    float thr = -v;
    int b;
    if (thr < mn2) b = 0;
    else { b = (int)((thr - mn2) * invw2) + 1; b = b > 1024 ? 1024 : b; }
    ws[OFF_SP + (unsigned)l * 64u + c] = v * hc[b] + hs[b];
  }
}

// ============================================================================
// K3b: gate pass. 256 blocks x 16 l-rows:
// p_gate = sigmoid(SP/512 @ Wa^T + ba); val = k*(1+gate); atomicMax PMAX.
// ============================================================================
__global__ __launch_bounds__(TPB) void k3b_gate(
    const float* __restrict__ Wa, const float* __restrict__ ba,
    float* __restrict__ ws)
{
  __shared__ float sp[16 * 64];
  __shared__ float wat[64 * 65];
  int bid = blockIdx.x, tid = threadIdx.x;
  int c = tid & 63, g = tid >> 6;
  int l0 = bid * 16;
  {                                     // stage SP tile (x 1/512)
    int idx = tid * 4;
    float4 v = *(const float4*)&ws[OFF_SP + (unsigned)l0 * 64u + idx];
    v.x *= (1.f / 512.f); v.y *= (1.f / 512.f);
    v.z *= (1.f / 512.f); v.w *= (1.f / 512.f);
    *(float4*)&sp[idx] = v;
  }
  for (int it = 0; it < 16; ++it) {     // WaT[c'][j] = Wa[j][c']
    int idx = it * TPB + tid;
    wat[(idx & 63) * 65 + (idx >> 6)] = Wa[idx];
  }
  __syncthreads();
  float vmax = 0.f;                     // vals >= 0 (k>=0, gate>0)
  float bac = ba[c];
#pragma unroll
  for (int i = 0; i < 4; ++i) {
    int ll = g * 4 + i;
    float dot = 0.f;
#pragma unroll 8
    for (int jj = 0; jj < 64; ++jj)
      dot += sp[ll * 64 + jj] * wat[jj * 65 + c];
    float pg = 1.f / (1.f + __expf(-(dot + bac)));
    float val = ws[OFF_K + (unsigned)(l0 + ll) * 64u + c] * (1.f + pg);
    vmax = fmaxf(vmax, val);
  }
  atomicMax((int*)&ws[OFF_PMAX + c], __float_as_int(vmax));
}

// ============================================================================
// K4: merged final stage, 32 blocks x 16 q. All matmul-shaped pieces as MFMA.
// ============================================================================
__global__ __launch_bounds__(TPB) void k4_final(
    const float* __restrict__ Wa,  const float* __restrict__ ba,
    const float* __restrict__ Wf1, const float* __restrict__ bf1,
    const float* __restrict__ Wf2, const float* __restrict__ bf2,
    const float* __restrict__ Wf3, const float* __restrict__ bf3,
    float* __restrict__ ws, float* __restrict__ out)
{
  __shared__ __align__(16) short mrb[16 * 72];     // mr bf16 (A for gate)
  __shared__ __align__(16) short wab[64 * 72];     // Wa bf16 (B for gate)
  __shared__ __align__(16) short ctxb[16 * 136];   // ctx bf16 (A for h1)
  __shared__ __align__(16) short h1b[16 * 264];    // h1 bf16 (A for h2)
  __shared__ __align__(16) short wgt[256 * 136];   // Wf1 [256][136] then Wf2 [128][264]
  __shared__ float red[64];
  int bid = blockIdx.x, tid = threadIdx.x;
  int q0 = bid * 16;
  int wave = tid >> 6, lane = tid & 63;
  int lm = lane & 15, quad = lane >> 4;

  {                                     // stage mr = SR/4096 -> bf16 [16][72]
    int q = tid >> 4, c4 = (tid & 15) * 4;
    float4 v = *(const float4*)&ws[OFF_SR + (unsigned)(q0 + q) * 64u + c4];
    uint2 st = make_uint2(pkbf(v.x * (1.f/4096.f), v.y * (1.f/4096.f)),
                          pkbf(v.z * (1.f/4096.f), v.w * (1.f/4096.f)));
    *(uint2*)&mrb[q * 72 + c4] = st;
  }
#pragma unroll
  for (int it = 0; it < 4; ++it) {      // stage Wa [64][64] -> bf16 [64][72]
    int i4 = it * TPB + tid;
    int row = i4 >> 4, c4 = (i4 & 15) * 4;
    float4 v = *(const float4*)&Wa[row * 64 + c4];
    uint2 st = make_uint2(pkbf(v.x, v.y), pkbf(v.z, v.w));
    *(uint2*)&wab[row * 72 + c4] = st;
  }
  __syncthreads();

  // gate MFMA: wave w -> c-tile [w*16, w*16+16)
  f32x4 gacc = {};
#pragma unroll
  for (int kc = 0; kc < 2; ++kc) {
    s16x8 a = *(const s16x8*)&mrb[lm * 72 + kc * 32 + quad * 8];
    s16x8 b = *(const s16x8*)&wab[(wave * 16 + lm) * 72 + kc * 32 + quad * 8];
    gacc = MFMA16(a, b, gacc);
  }
  {                                     // epilogue: rx + prot halves -> ctxb
    int c = wave * 16 + lm;
    float bac = ba[c];
    short pb = f2bf(ws[OFF_PMAX + c]);  // prot[c] (atomicMax result, fp32 bits)
#pragma unroll
    for (int r = 0; r < 4; ++r) {
      int q = quad * 4 + r;
      float gg = 1.f / (1.f + __expf(-(gacc[r] + bac)));
      float rv = ws[OFF_R + (unsigned)(q0 + q) * 64u + c];
      ctxb[q * 136 + c]      = f2bf(rv * (1.f + gg));
      ctxb[q * 136 + 64 + c] = pb;
    }
  }
#pragma unroll 4
  for (int it = 0; it < 32; ++it) {     // stage Wf1 [256][128] -> wgt [256][136]
    int i4 = it * TPB + tid;
    int row = i4 >> 5, c4 = (i4 & 31) * 4;
    float4 v = *(const float4*)&Wf1[row * 128 + c4];
    uint2 st = make_uint2(pkbf(v.x, v.y), pkbf(v.z, v.w));
    *(uint2*)&wgt[row * 136 + c4] = st;
  }
  __syncthreads();

  // h1 MFMA: wave w covers n in [w*64, w*64+64): 4 n-tiles x 4 k-chunks
  f32x4 h[4] = {};
#pragma unroll
  for (int kc = 0; kc < 4; ++kc) {
    s16x8 a = *(const s16x8*)&ctxb[lm * 136 + kc * 32 + quad * 8];
#pragma unroll
    for (int nt = 0; nt < 4; ++nt) {
      s16x8 b = *(const s16x8*)&wgt[(wave * 64 + nt * 16 + lm) * 136 + kc * 32 + quad * 8];
      h[nt] = MFMA16(a, b, h[nt]);
    }
  }
#pragma unroll
  for (int nt = 0; nt < 4; ++nt) {
    int n = wave * 64 + nt * 16 + lm;
    float bb = bf1[n];
#pragma unroll
    for (int r = 0; r < 4; ++r) {
      int q = quad * 4 + r;
      float v = h[nt][r] + bb;
      v = v > 0.f ? v : 0.01f * v;
      h1b[q * 264 + n] = f2bf(v);
    }
  }
  __syncthreads();                      // h1b complete; wgt reads done

#pragma unroll 4
  for (int it = 0; it < 32; ++it) {     // stage Wf2 [128][256] -> wgt [128][264]
    int i4 = it * TPB + tid;
    int row = i4 >> 6, c4 = (i4 & 63) * 4;
    float4 v = *(const float4*)&Wf2[row * 256 + c4];
    uint2 st = make_uint2(pkbf(v.x, v.y), pkbf(v.z, v.w));
    *(uint2*)&wgt[row * 264 + c4] = st;
  }
  __syncthreads();

  // h2 MFMA: wave w covers m in [w*32, w*32+32): 2 n-tiles x 8 k-chunks
  f32x4 o[2] = {};
#pragma unroll
  for (int kc = 0; kc < 8; ++kc) {
    s16x8 a = *(const s16x8*)&h1b[lm * 264 + kc * 32 + quad * 8];
#pragma unroll
    for (int nt = 0; nt < 2; ++nt) {
      s16x8 b = *(const s16x8*)&wgt[(wave * 32 + nt * 16 + lm) * 264 + kc * 32 + quad * 8];
      o[nt] = MFMA16(a, b, o[nt]);
    }
  }
  float pv[4] = {0.f, 0.f, 0.f, 0.f};
#pragma unroll
  for (int nt = 0; nt < 2; ++nt) {
    int m = wave * 32 + nt * 16 + lm;
    float bb = bf2[m], w3 = Wf3[m];
#pragma unroll
    for (int r = 0; r < 4; ++r) {
      float v = o[nt][r] + bb;
      v = v > 0.f ? v : 0.01f * v;
      pv[r] += v * w3;
    }
  }
#pragma unroll
  for (int msk = 1; msk < 16; msk <<= 1)
#pragma unroll
    for (int r = 0; r < 4; ++r) pv[r] += __shfl_xor(pv[r], msk);
  if (lm == 0) {
#pragma unroll
    for (int r = 0; r < 4; ++r) red[(quad * 4 + r) * 4 + wave] = pv[r];
  }
  __syncthreads();
  if (tid < 16)
    out[q0 + tid] = red[tid * 4] + red[tid * 4 + 1] + red[tid * 4 + 2] +
                    red[tid * 4 + 3] + bf3[0];
}

// ============================================================================
extern "C" void kernel_launch(void* const* d_in, const int* in_sizes, int n_in,
                              void* d_out, int out_size, void* d_ws, size_t ws_size,
                              hipStream_t stream)
{
  const float* reactions = (const float*)d_in[0];
  const float* protein   = (const float*)d_in[1];
  const float* Wc  = (const float*)d_in[2];
  const float* bc  = (const float*)d_in[3];
  const float* W1  = (const float*)d_in[4];
  const float* b1  = (const float*)d_in[5];
  const float* W2  = (const float*)d_in[6];
  const float* b2  = (const float*)d_in[7];
  const float* Wa  = (const float*)d_in[8];
  const float* ba  = (const float*)d_in[9];
  const float* Wpa = (const float*)d_in[10];
  const float* bpa = (const float*)d_in[11];
  const float* Wra = (const float*)d_in[12];
  const float* bra = (const float*)d_in[13];
  const float* Wf1 = (const float*)d_in[14];
  const float* bf1 = (const float*)d_in[15];
  const float* Wf2 = (const float*)d_in[16];
  const float* bf2 = (const float*)d_in[17];
  const float* Wf3 = (const float*)d_in[18];
  const float* bf3 = (const float*)d_in[19];
  float* ws  = (float*)d_ws;
  float* out = (float*)d_out;

  hipLaunchKernelGGL(k1_gemm, dim3(513), dim3(TPB), 0, stream,
                     protein, Wc, bc, ws);
  hipLaunchKernelGGL(k2_heads, dim3(144), dim3(TPB), 0, stream,
                     reactions, W1, b1, W2, b2, Wpa, bpa, Wra, bra, ws);
  hipLaunchKernelGGL(k3h_hist, dim3(64), dim3(TPB), 0, stream, ws);
  hipLaunchKernelGGL(k3b_gate, dim3(256), dim3(TPB), 0, stream, Wa, ba, ws);
  hipLaunchKernelGGL(k4_final, dim3(32), dim3(TPB), 0, stream,
                     Wa, ba, Wf1, bf1, Wf2, bf2, Wf3, bf3, ws, out);
}

// Round 12
// 169.979 us; speedup vs baseline: 1.0499x; 1.0499x over previous
//
#include <hip/hip_runtime.h>
#include <hip/hip_bf16.h>
#include <math.h>

#define TPB 256

typedef __attribute__((ext_vector_type(8))) short s16x8;
typedef __attribute__((ext_vector_type(4))) float f32x4;

#define MFMA16(a, b, c) __builtin_amdgcn_mfma_f32_16x16x32_bf16((a), (b), (c), 0, 0, 0)

// ---------------- workspace layout (float offsets) ----------------
constexpr unsigned OFF_P    = 0u;                     // p    [4096][256] (relu'd)
constexpr unsigned OFF_K    = OFF_P    + 4096u*256u;  // k    [4096][64]
constexpr unsigned OFF_PA   = OFF_K    + 4096u*64u;   // pa   [4096][64]
constexpr unsigned OFF_R    = OFF_PA   + 4096u*64u;   // r    [512][64]
constexpr unsigned OFF_RA   = OFF_R    + 512u*64u;    // ra   [512][64]
constexpr unsigned OFF_SR   = OFF_RA   + 512u*64u;    // SR   [512][64]  (k3h)
constexpr unsigned OFF_PMAX = OFF_SR   + 512u*64u;    // PMAX [64] (atomicMax, zeroed by k1 tail)
constexpr unsigned OFF_SP   = OFF_PMAX + 64u;         // SP   [4096][64] (k3h)
constexpr unsigned OFF_PAT  = OFF_SP   + 4096u*64u;   // paT  [64][4096] (k2)
constexpr unsigned OFF_RAT  = OFF_PAT  + 64u*4096u;   // raT  [64][512]  (k2)

// scalar RNE fp32 -> bf16
__device__ __forceinline__ short f2bf(float x) {
  union { float f; unsigned u; } v; v.f = x;
  unsigned r = v.u + 0x7FFFu + ((v.u >> 16) & 1u);
  return (short)(r >> 16);
}
// packed RNE: 2 floats -> 2 bf16 in one dword
__device__ __forceinline__ unsigned pkbf(float a, float b) {
  __hip_bfloat162 h = __float22bfloat162_rn(make_float2(a, b));
  union { __hip_bfloat162 h2; unsigned u; } v; v.h2 = h;
  return v.u;
}
union U8 { s16x8 s; unsigned u[4]; };

// ============================================================================
// K1: p = relu(protein @ Wc^T + bc)  via bf16 MFMA 16x16x32.
// 512 GEMM blocks (tile 32x64) -> 2 blocks/CU. BK=64, 16 chunks, prefetch.
// Tail block 512: zero PMAX.
// ============================================================================
__global__ __launch_bounds__(TPB, 2) void k1_gemm(
    const float* __restrict__ prot, const float* __restrict__ Wc,
    const float* __restrict__ bc,   float* __restrict__ ws)
{
  int bid = blockIdx.x;
  int tid = threadIdx.x;
  if (bid >= 512) {
    if (tid < 16)
      *(float4*)&ws[OFF_PMAX + tid * 4] = make_float4(0.f, 0.f, 0.f, 0.f);
    return;
  }

  __shared__ __align__(16) short Asm[32 * 72];    // [m][64+8] bf16
  __shared__ __align__(16) short Bsm[64 * 72];    // [n][64+8] bf16

  int m0 = (bid >> 2) * 32;
  int n0 = (bid & 3) * 64;
  int wave = tid >> 6, lane = tid & 63;
  int wm = (wave & 1) * 16, wn = (wave >> 1) * 32;   // wave tile 16x32
  int lm = lane & 15, quad = lane >> 4;

  int arow = tid >> 3, aseg = (tid & 7) * 8;    // A: 32 rows x 8 x 8 floats
  int brow = tid >> 2, bseg = (tid & 3) * 16;   // B: 64 rows x 4 x 16 floats

  const float* Ag = prot + (size_t)(m0 + arow) * 1024 + aseg;
  const float* Bg = Wc   + (size_t)(n0 + brow) * 1024 + bseg;

  float4 a4[2], b4[4];
#pragma unroll
  for (int i = 0; i < 2; ++i) a4[i] = *(const float4*)(Ag + i * 4);
#pragma unroll
  for (int i = 0; i < 4; ++i) b4[i] = *(const float4*)(Bg + i * 4);

  f32x4 acc[2] = {};

  for (int kc = 0; kc < 16; ++kc) {
    __syncthreads();                    // previous chunk's frag reads done
    {
      U8 s;
      s.u[0] = pkbf(a4[0].x, a4[0].y); s.u[1] = pkbf(a4[0].z, a4[0].w);
      s.u[2] = pkbf(a4[1].x, a4[1].y); s.u[3] = pkbf(a4[1].z, a4[1].w);
      *(s16x8*)&Asm[arow * 72 + aseg] = s.s;
    }
#pragma unroll
    for (int h = 0; h < 2; ++h) {
      U8 s;
      s.u[0] = pkbf(b4[h*2].x,   b4[h*2].y);
      s.u[1] = pkbf(b4[h*2].z,   b4[h*2].w);
      s.u[2] = pkbf(b4[h*2+1].x, b4[h*2+1].y);
      s.u[3] = pkbf(b4[h*2+1].z, b4[h*2+1].w);
      *(s16x8*)&Bsm[brow * 72 + bseg + h * 8] = s.s;
    }
    if (kc < 15) {                      // prefetch next chunk over this MFMA
#pragma unroll
      for (int i = 0; i < 2; ++i) a4[i] = *(const float4*)(Ag + (kc + 1) * 64 + i * 4);
#pragma unroll
      for (int i = 0; i < 4; ++i) b4[i] = *(const float4*)(Bg + (kc + 1) * 64 + i * 4);
    }
    __syncthreads();
#pragma unroll
    for (int ks = 0; ks < 2; ++ks) {
      s16x8 af = *(const s16x8*)&Asm[(wm + lm) * 72 + ks * 32 + quad * 8];
#pragma unroll
      for (int ni = 0; ni < 2; ++ni) {
        s16x8 bfv = *(const s16x8*)&Bsm[(wn + ni * 16 + lm) * 72 + ks * 32 + quad * 8];
        acc[ni] = MFMA16(af, bfv, acc[ni]);
      }
    }
  }

  // epilogue: C/D layout col=lane&15, row=quad*4+reg
#pragma unroll
  for (int ni = 0; ni < 2; ++ni) {
    int col = n0 + wn + ni * 16 + lm;
    float bcv = bc[col];
#pragma unroll
    for (int r = 0; r < 4; ++r) {
      int row = m0 + wm + quad * 4 + r;
      ws[OFF_P + (unsigned)row * 256u + col] = fmaxf(acc[ni][r] + bcv, 0.f);
    }
  }
}

// ============================================================================
// K2: two heads via bf16 MFMA, 144 blocks x 32 rows, both stages fused.
// NEW: also writes transposed pa/ra (paT [64][4096], raT [64][512]) so k3h's
// column gathers become contiguous coalesced loads. Scattered STORES are
// fire-and-forget (no dependent wait) - cheap, unlike k3h's old scattered
// dependent LOADS.
// ============================================================================
__global__ __launch_bounds__(TPB, 2) void k2_heads(
    const float* __restrict__ reactions,
    const float* __restrict__ W1,  const float* __restrict__ b1,
    const float* __restrict__ W2,  const float* __restrict__ b2,
    const float* __restrict__ Wpa, const float* __restrict__ bpa,
    const float* __restrict__ Wra, const float* __restrict__ bra,
    float* __restrict__ ws)
{
  __shared__ __align__(16) short Asm[32 * 264];   // src rows [32][256+8]
  __shared__ __align__(16) short Bsm[64 * 264];   // W1/W2 [64][256+8]
  __shared__ __align__(16) short Ksm[32 * 72];    // k-tile bf16 [32][64+8]
  __shared__ __align__(16) short Wsm[64 * 72];    // Wpa/Wra [64][64+8]
  int bid = blockIdx.x, tid = threadIdx.x;
  bool isProt = bid < 128;
  int row0 = (isProt ? bid : (bid - 128)) * 32;
  const float* src  = isProt ? (ws + OFF_P) : reactions;
  const float* Wst1 = isProt ? W1 : W2;
  const float* bv   = isProt ? b1 : b2;
  const float* Wst2 = isProt ? Wpa : Wra;
  const float* b2nd = isProt ? bpa : bra;
  float* out1  = ws + (isProt ? OFF_K : OFF_R);
  float* out2  = ws + (isProt ? OFF_PA : OFF_RA);
  float* out2T = ws + (isProt ? OFF_PAT : OFF_RAT);
  unsigned tstride = isProt ? 4096u : 512u;

  {                                     // stage A [32][256] fp32 -> bf16
    int row = tid >> 3, seg = (tid & 7) * 32;
    const float* sp = src + (size_t)(row0 + row) * 256 + seg;
    float4 f[8];
#pragma unroll
    for (int i = 0; i < 8; ++i) f[i] = *(const float4*)(sp + i * 4);
#pragma unroll
    for (int i = 0; i < 4; ++i) {
      U8 s;
      s.u[0] = pkbf(f[2*i].x,   f[2*i].y);
      s.u[1] = pkbf(f[2*i].z,   f[2*i].w);
      s.u[2] = pkbf(f[2*i+1].x, f[2*i+1].y);
      s.u[3] = pkbf(f[2*i+1].z, f[2*i+1].w);
      *(s16x8*)&Asm[row * 264 + seg + i * 8] = s.s;
    }
  }
  {                                     // stage B = W1/W2 [64][256] native
    int row = tid >> 2, seg = (tid & 3) * 64;
    const float* sp = Wst1 + (size_t)row * 256 + seg;
#pragma unroll
    for (int i = 0; i < 8; ++i) {
      float4 fa = *(const float4*)(sp + i * 8);
      float4 fb = *(const float4*)(sp + i * 8 + 4);
      U8 s;
      s.u[0] = pkbf(fa.x, fa.y); s.u[1] = pkbf(fa.z, fa.w);
      s.u[2] = pkbf(fb.x, fb.y); s.u[3] = pkbf(fb.z, fb.w);
      *(s16x8*)&Bsm[row * 264 + seg + i * 8] = s.s;
    }
  }
  {                                     // stage Wpa/Wra [64][64] native
    int row = tid >> 2, seg = (tid & 3) * 16;
    const float* sp = Wst2 + (size_t)row * 64 + seg;
#pragma unroll
    for (int i = 0; i < 2; ++i) {
      float4 fa = *(const float4*)(sp + i * 8);
      float4 fb = *(const float4*)(sp + i * 8 + 4);
      U8 s;
      s.u[0] = pkbf(fa.x, fa.y); s.u[1] = pkbf(fa.z, fa.w);
      s.u[2] = pkbf(fb.x, fb.y); s.u[3] = pkbf(fb.z, fb.w);
      *(s16x8*)&Wsm[row * 72 + seg + i * 8] = s.s;
    }
  }
  __syncthreads();

  int wave = tid >> 6, lane = tid & 63;
  int lm = lane & 15, quad = lane >> 4;
  int wm = (wave >> 1) * 16, wn = (wave & 1) * 32;   // wave tile 16x32

  f32x4 acc[2] = {};
#pragma unroll
  for (int kc = 0; kc < 8; ++kc) {
    s16x8 a = *(const s16x8*)&Asm[(wm + lm) * 264 + kc * 32 + quad * 8];
#pragma unroll
    for (int ni = 0; ni < 2; ++ni) {
      s16x8 b = *(const s16x8*)&Bsm[(wn + ni * 16 + lm) * 264 + kc * 32 + quad * 8];
      acc[ni] = MFMA16(a, b, acc[ni]);
    }
  }
  // epilogue 1: k = relu(acc + b); fp32 -> ws, bf16 -> Ksm (A-layout)
#pragma unroll
  for (int ni = 0; ni < 2; ++ni) {
    int col = wn + ni * 16 + lm;
    float bb = bv[col];
#pragma unroll
    for (int r = 0; r < 4; ++r) {
      int row = wm + quad * 4 + r;
      float kv = fmaxf(acc[ni][r] + bb, 0.f);
      out1[(size_t)(row0 + row) * 64 + col] = kv;
      Ksm[row * 72 + col] = f2bf(kv);
    }
  }
  __syncthreads();

  f32x4 acc2[2] = {};
#pragma unroll
  for (int kc = 0; kc < 2; ++kc) {
    s16x8 a = *(const s16x8*)&Ksm[(wm + lm) * 72 + kc * 32 + quad * 8];
#pragma unroll
    for (int ni = 0; ni < 2; ++ni) {
      s16x8 b = *(const s16x8*)&Wsm[(wn + ni * 16 + lm) * 72 + kc * 32 + quad * 8];
      acc2[ni] = MFMA16(a, b, acc2[ni]);
    }
  }
#pragma unroll
  for (int ni = 0; ni < 2; ++ni) {
    int col = wn + ni * 16 + lm;
    float bb = b2nd[col];
#pragma unroll
    for (int r = 0; r < 4; ++r) {
      int row = wm + quad * 4 + r;
      float v = acc2[ni][r] + bb;
      out2[(size_t)(row0 + row) * 64 + col] = v;
      out2T[(size_t)col * tstride + (row0 + row)] = v;   // transposed copy
    }
  }
}

// ============================================================================
// K3h: HISTOGRAM interaction sums, LATENCY-FIXED (R11 ran 64 blocks with
// one-64B-line-per-element column gathers - ~45us of pure exposure hiding
// under the 42us fill in top-5; that's why R11 was neutral).
// Now: 128 blocks (pass A and pass B split), columns staged from the k2-
// written TRANSPOSED copies as contiguous coalesced float4 reads.
// Algorithm bit-identical to R11 (correctness-verified, absmax 0.0039):
//   Sr[q,c] = u*cnt(x > -u) + sum(x > -u) via 1024-bin hist + suffix scan.
//   bid<64 : pass A: hist of pa-column c -> 512 SR queries
//   bid>=64: pass B: hist of ra-column c -> 4096 SP queries
// ============================================================================
__global__ __launch_bounds__(TPB) void k3h_hist(float* __restrict__ ws)
{
  __shared__ float xcol[4096];          // pa column
  __shared__ float rcol[512];           // ra column
  __shared__ float hc[1025];            // bin counts -> suffix counts
  __shared__ float hs[1025];            // bin sums   -> suffix sums
  __shared__ float rmn[4], rmx[4];
  int bid = blockIdx.x, tid = threadIdx.x;
  int wave = tid >> 6, lane = tid & 63;
  bool passA = bid < 64;
  int c = passA ? bid : (bid - 64);
  const float* paT = ws + OFF_PAT + (size_t)c * 4096;
  const float* raT = ws + OFF_RAT + (size_t)c * 512;

  // coalesced staging: contiguous float4 reads
  for (int i = tid * 4; i < 4096; i += TPB * 4)
    *(float4*)&xcol[i] = *(const float4*)(paT + i);
  if (tid * 4 < 512)
    *(float4*)&rcol[tid * 4] = *(const float4*)(raT + tid * 4);
  for (int i = tid; i < 1025; i += TPB) { hc[i] = 0.f; hs[i] = 0.f; }
  __syncthreads();

  const float* hsrc = passA ? xcol : rcol;  // histogram source
  int hn = passA ? 4096 : 512;
  // min/max
  float mn = 1e30f, mx = -1e30f;
  for (int i = tid; i < hn; i += TPB) {
    float x = hsrc[i];
    mn = fminf(mn, x); mx = fmaxf(mx, x);
  }
#pragma unroll
  for (int off = 32; off > 0; off >>= 1) {
    mn = fminf(mn, __shfl_down(mn, off));
    mx = fmaxf(mx, __shfl_down(mx, off));
  }
  if (lane == 0) { rmn[wave] = mn; rmx[wave] = mx; }
  __syncthreads();
  mn = fminf(fminf(rmn[0], rmn[1]), fminf(rmn[2], rmn[3]));
  mx = fmaxf(fmaxf(rmx[0], rmx[1]), fmaxf(rmx[2], rmx[3]));
  float w = (mx - mn) * (1.f / 1024.f);
  float invw = (w > 1e-30f) ? 1.f / w : 0.f;
  // histogram
  for (int i = tid; i < hn; i += TPB) {
    float x = hsrc[i];
    int b = (int)((x - mn) * invw);
    b = b < 0 ? 0 : (b > 1023 ? 1023 : b);
    atomicAdd(&hc[b], 1.f);
    atomicAdd(&hs[b], x);
  }
  __syncthreads();
  if (wave == 0) {                      // suffix scan, 16 bins/lane + shfl
    float vc[16], vs[16], sc = 0.f, ss = 0.f;
#pragma unroll
    for (int i = 0; i < 16; ++i) {
      vc[i] = hc[lane * 16 + i]; sc += vc[i];
      vs[i] = hs[lane * 16 + i]; ss += vs[i];
    }
    float tc = sc, ts = ss;
#pragma unroll
    for (int off = 1; off < 64; off <<= 1) {
      float oc = __shfl_down(tc, off);
      float os = __shfl_down(ts, off);
      if (lane + off < 64) { tc += oc; ts += os; }
    }
    float runc = tc - sc, runs = ts - ss;
#pragma unroll
    for (int i = 15; i >= 0; --i) {
      runc += vc[i]; hc[lane * 16 + i] = runc;
      runs += vs[i]; hs[lane * 16 + i] = runs;
    }
  }
  __syncthreads();                      // hc/hs = inclusive suffix; [1024]=0

  if (passA) {                          // 512 SR queries (u from rcol)
    for (int q = tid; q < 512; q += TPB) {
      float u = rcol[q];
      float thr = -u;
      int b;
      if (thr < mn) b = 0;
      else { b = (int)((thr - mn) * invw) + 1; b = b > 1024 ? 1024 : b; }
      ws[OFF_SR + (unsigned)q * 64u + c] = u * hc[b] + hs[b];
    }
  } else {                              // 4096 SP queries (v from xcol)
    for (int l = tid; l < 4096; l += TPB) {
      float v = xcol[l];
      float thr = -v;
      int b;
      if (thr < mn) b = 0;
      else { b = (int)((thr - mn) * invw) + 1; b = b > 1024 ? 1024 : b; }
      ws[OFF_SP + (unsigned)l * 64u + c] = v * hc[b] + hs[b];
    }
  }
}

// ============================================================================
// K3b: gate pass. 256 blocks x 16 l-rows:
// p_gate = sigmoid(SP/512 @ Wa^T + ba); val = k*(1+gate); atomicMax PMAX.
// ============================================================================
__global__ __launch_bounds__(TPB) void k3b_gate(
    const float* __restrict__ Wa, const float* __restrict__ ba,
    float* __restrict__ ws)
{
  __shared__ float sp[16 * 64];
  __shared__ float wat[64 * 65];
  int bid = blockIdx.x, tid = threadIdx.x;
  int c = tid & 63, g = tid >> 6;
  int l0 = bid * 16;
  {                                     // stage SP tile (x 1/512)
    int idx = tid * 4;
    float4 v = *(const float4*)&ws[OFF_SP + (unsigned)l0 * 64u + idx];
    v.x *= (1.f / 512.f); v.y *= (1.f / 512.f);
    v.z *= (1.f / 512.f); v.w *= (1.f / 512.f);
    *(float4*)&sp[idx] = v;
  }
  for (int it = 0; it < 16; ++it) {     // WaT[c'][j] = Wa[j][c']
    int idx = it * TPB + tid;
    wat[(idx & 63) * 65 + (idx >> 6)] = Wa[idx];
  }
  __syncthreads();
  float vmax = 0.f;                     // vals >= 0 (k>=0, gate>0)
  float bac = ba[c];
#pragma unroll
  for (int i = 0; i < 4; ++i) {
    int ll = g * 4 + i;
    float dot = 0.f;
#pragma unroll 8
    for (int jj = 0; jj < 64; ++jj)
      dot += sp[ll * 64 + jj] * wat[jj * 65 + c];
    float pg = 1.f / (1.f + __expf(-(dot + bac)));
    float val = ws[OFF_K + (unsigned)(l0 + ll) * 64u + c] * (1.f + pg);
    vmax = fmaxf(vmax, val);
  }
  atomicMax((int*)&ws[OFF_PMAX + c], __float_as_int(vmax));
}

// ============================================================================
// K4: merged final stage, 32 blocks x 16 q. All matmul-shaped pieces as MFMA.
// ============================================================================
__global__ __launch_bounds__(TPB) void k4_final(
    const float* __restrict__ Wa,  const float* __restrict__ ba,
    const float* __restrict__ Wf1, const float* __restrict__ bf1,
    const float* __restrict__ Wf2, const float* __restrict__ bf2,
    const float* __restrict__ Wf3, const float* __restrict__ bf3,
    float* __restrict__ ws, float* __restrict__ out)
{
  __shared__ __align__(16) short mrb[16 * 72];     // mr bf16 (A for gate)
  __shared__ __align__(16) short wab[64 * 72];     // Wa bf16 (B for gate)
  __shared__ __align__(16) short ctxb[16 * 136];   // ctx bf16 (A for h1)
  __shared__ __align__(16) short h1b[16 * 264];    // h1 bf16 (A for h2)
  __shared__ __align__(16) short wgt[256 * 136];   // Wf1 [256][136] then Wf2 [128][264]
  __shared__ float red[64];
  int bid = blockIdx.x, tid = threadIdx.x;
  int q0 = bid * 16;
  int wave = tid >> 6, lane = tid & 63;
  int lm = lane & 15, quad = lane >> 4;

  {                                     // stage mr = SR/4096 -> bf16 [16][72]
    int q = tid >> 4, c4 = (tid & 15) * 4;
    float4 v = *(const float4*)&ws[OFF_SR + (unsigned)(q0 + q) * 64u + c4];
    uint2 st = make_uint2(pkbf(v.x * (1.f/4096.f), v.y * (1.f/4096.f)),
                          pkbf(v.z * (1.f/4096.f), v.w * (1.f/4096.f)));
    *(uint2*)&mrb[q * 72 + c4] = st;
  }
#pragma unroll
  for (int it = 0; it < 4; ++it) {      // stage Wa [64][64] -> bf16 [64][72]
    int i4 = it * TPB + tid;
    int row = i4 >> 4, c4 = (i4 & 15) * 4;
    float4 v = *(const float4*)&Wa[row * 64 + c4];
    uint2 st = make_uint2(pkbf(v.x, v.y), pkbf(v.z, v.w));
    *(uint2*)&wab[row * 72 + c4] = st;
  }
  __syncthreads();

  // gate MFMA: wave w -> c-tile [w*16, w*16+16)
  f32x4 gacc = {};
#pragma unroll
  for (int kc = 0; kc < 2; ++kc) {
    s16x8 a = *(const s16x8*)&mrb[lm * 72 + kc * 32 + quad * 8];
    s16x8 b = *(const s16x8*)&wab[(wave * 16 + lm) * 72 + kc * 32 + quad * 8];
    gacc = MFMA16(a, b, gacc);
  }
  {                                     // epilogue: rx + prot halves -> ctxb
    int c = wave * 16 + lm;
    float bac = ba[c];
    short pb = f2bf(ws[OFF_PMAX + c]);  // prot[c] (atomicMax result, fp32 bits)
#pragma unroll
    for (int r = 0; r < 4; ++r) {
      int q = quad * 4 + r;
      float gg = 1.f / (1.f + __expf(-(gacc[r] + bac)));
      float rv = ws[OFF_R + (unsigned)(q0 + q) * 64u + c];
      ctxb[q * 136 + c]      = f2bf(rv * (1.f + gg));
      ctxb[q * 136 + 64 + c] = pb;
    }
  }
#pragma unroll 4
  for (int it = 0; it < 32; ++it) {     // stage Wf1 [256][128] -> wgt [256][136]
    int i4 = it * TPB + tid;
    int row = i4 >> 5, c4 = (i4 & 31) * 4;
    float4 v = *(const float4*)&Wf1[row * 128 + c4];
    uint2 st = make_uint2(pkbf(v.x, v.y), pkbf(v.z, v.w));
    *(uint2*)&wgt[row * 136 + c4] = st;
  }
  __syncthreads();

  // h1 MFMA: wave w covers n in [w*64, w*64+64): 4 n-tiles x 4 k-chunks
  f32x4 h[4] = {};
#pragma unroll
  for (int kc = 0; kc < 4; ++kc) {
    s16x8 a = *(const s16x8*)&ctxb[lm * 136 + kc * 32 + quad * 8];
#pragma unroll
    for (int nt = 0; nt < 4; ++nt) {
      s16x8 b = *(const s16x8*)&wgt[(wave * 64 + nt * 16 + lm) * 136 + kc * 32 + quad * 8];
      h[nt] = MFMA16(a, b, h[nt]);
    }
  }
#pragma unroll
  for (int nt = 0; nt < 4; ++nt) {
    int n = wave * 64 + nt * 16 + lm;
    float bb = bf1[n];
#pragma unroll
    for (int r = 0; r < 4; ++r) {
      int q = quad * 4 + r;
      float v = h[nt][r] + bb;
      v = v > 0.f ? v : 0.01f * v;
      h1b[q * 264 + n] = f2bf(v);
    }
  }
  __syncthreads();                      // h1b complete; wgt reads done

#pragma unroll 4
  for (int it = 0; it < 32; ++it) {     // stage Wf2 [128][256] -> wgt [128][264]
    int i4 = it * TPB + tid;
    int row = i4 >> 6, c4 = (i4 & 63) * 4;
    float4 v = *(const float4*)&Wf2[row * 256 + c4];
    uint2 st = make_uint2(pkbf(v.x, v.y), pkbf(v.z, v.w));
    *(uint2*)&wgt[row * 264 + c4] = st;
  }
  __syncthreads();

  // h2 MFMA: wave w covers m in [w*32, w*32+32): 2 n-tiles x 8 k-chunks
  f32x4 o[2] = {};
#pragma unroll
  for (int kc = 0; kc < 8; ++kc) {
    s16x8 a = *(const s16x8*)&h1b[lm * 264 + kc * 32 + quad * 8];
#pragma unroll
    for (int nt = 0; nt < 2; ++nt) {
      s16x8 b = *(const s16x8*)&wgt[(wave * 32 + nt * 16 + lm) * 264 + kc * 32 + quad * 8];
      o[nt] = MFMA16(a, b, o[nt]);
    }
  }
  float pv[4] = {0.f, 0.f, 0.f, 0.f};
#pragma unroll
  for (int nt = 0; nt < 2; ++nt) {
    int m = wave * 32 + nt * 16 + lm;
    float bb = bf2[m], w3 = Wf3[m];
#pragma unroll
    for (int r = 0; r < 4; ++r) {
      float v = o[nt][r] + bb;
      v = v > 0.f ? v : 0.01f * v;
      pv[r] += v * w3;
    }
  }
#pragma unroll
  for (int msk = 1; msk < 16; msk <<= 1)
#pragma unroll
    for (int r = 0; r < 4; ++r) pv[r] += __shfl_xor(pv[r], msk);
  if (lm == 0) {
#pragma unroll
    for (int r = 0; r < 4; ++r) red[(quad * 4 + r) * 4 + wave] = pv[r];
  }
  __syncthreads();
  if (tid < 16)
    out[q0 + tid] = red[tid * 4] + red[tid * 4 + 1] + red[tid * 4 + 2] +
                    red[tid * 4 + 3] + bf3[0];
}

// ============================================================================
extern "C" void kernel_launch(void* const* d_in, const int* in_sizes, int n_in,
                              void* d_out, int out_size, void* d_ws, size_t ws_size,
                              hipStream_t stream)
{
  const float* reactions = (const float*)d_in[0];
  const float* protein   = (const float*)d_in[1];
  const float* Wc  = (const float*)d_in[2];
  const float* bc  = (const float*)d_in[3];
  const float* W1  = (const float*)d_in[4];
  const float* b1  = (const float*)d_in[5];
  const float* W2  = (const float*)d_in[6];
  const float* b2  = (const float*)d_in[7];
  const float* Wa  = (const float*)d_in[8];
  const float* ba  = (const float*)d_in[9];
  const float* Wpa = (const float*)d_in[10];
  const float* bpa = (const float*)d_in[11];
  const float* Wra = (const float*)d_in[12];
  const float* bra = (const float*)d_in[13];
  const float* Wf1 = (const float*)d_in[14];
  const float* bf1 = (const float*)d_in[15];
  const float* Wf2 = (const float*)d_in[16];
  const float* bf2 = (const float*)d_in[17];
  const float* Wf3 = (const float*)d_in[18];
  const float* bf3 = (const float*)d_in[19];
  float* ws  = (float*)d_ws;
  float* out = (float*)d_out;

  hipLaunchKernelGGL(k1_gemm, dim3(513), dim3(TPB), 0, stream,
                     protein, Wc, bc, ws);
  hipLaunchKernelGGL(k2_heads, dim3(144), dim3(TPB), 0, stream,
                     reactions, W1, b1, W2, b2, Wpa, bpa, Wra, bra, ws);
  hipLaunchKernelGGL(k3h_hist, dim3(128), dim3(TPB), 0, stream, ws);
  hipLaunchKernelGGL(k3b_gate, dim3(256), dim3(TPB), 0, stream, Wa, ba, ws);
  hipLaunchKernelGGL(k4_final, dim3(32), dim3(TPB), 0, stream,
                     Wa, ba, Wf1, bf1, Wf2, bf2, Wf3, bf3, ws, out);
}